// Round 9
// baseline (538.072 us; speedup 1.0000x reference)
//
#include <hip/hip_runtime.h>
#include <stdint.h>

#define NB 8
#define NPTS 100000
#define NS 4096
#define NN 32
#define NCH 64
#define CLG 18
#define CELLS (1 << CLG)           // 64^3 dense voxel cells per batch
#define CMASK (CELLS - 1)

// d_out float layout (element offsets)
#define OUT_MAIN 0ull                          // [8,4096,32,67]
#define OUT_SRC  70254592ull                   // [8,4096,32]
#define OUT_CTR  71303168ull                   // [8,4096]
#define OUT_CF   71335936ull                   // [8,100000]
#define OUT_SF   72135936ull                   // [8,100000]

typedef float f32x4 __attribute__((ext_vector_type(4)));

__host__ __device__ static inline uint32_t rotl32(uint32_t v, int d) {
    return (v << d) | (v >> (32 - d));
}

// JAX threefry2x32 (5 groups of 4 rounds), exact.
__host__ __device__ static inline void tf2x32(uint32_t k0, uint32_t k1,
                                              uint32_t x0, uint32_t x1,
                                              uint32_t& o0, uint32_t& o1) {
    uint32_t ks2 = k0 ^ k1 ^ 0x1BD11BDAu;
    x0 += k0; x1 += k1;
    x0 += x1; x1 = rotl32(x1, 13); x1 ^= x0;
    x0 += x1; x1 = rotl32(x1, 15); x1 ^= x0;
    x0 += x1; x1 = rotl32(x1, 26); x1 ^= x0;
    x0 += x1; x1 = rotl32(x1, 6);  x1 ^= x0;
    x0 += k1; x1 += ks2 + 1u;
    x0 += x1; x1 = rotl32(x1, 17); x1 ^= x0;
    x0 += x1; x1 = rotl32(x1, 29); x1 ^= x0;
    x0 += x1; x1 = rotl32(x1, 16); x1 ^= x0;
    x0 += x1; x1 = rotl32(x1, 24); x1 ^= x0;
    x0 += ks2; x1 += k0 + 2u;
    x0 += x1; x1 = rotl32(x1, 13); x1 ^= x0;
    x0 += x1; x1 = rotl32(x1, 15); x1 ^= x0;
    x0 += x1; x1 = rotl32(x1, 26); x1 ^= x0;
    x0 += x1; x1 = rotl32(x1, 6);  x1 ^= x0;
    x0 += k0; x1 += k1 + 3u;
    x0 += x1; x1 = rotl32(x1, 17); x1 ^= x0;
    x0 += x1; x1 = rotl32(x1, 29); x1 ^= x0;
    x0 += x1; x1 = rotl32(x1, 16); x1 ^= x0;
    x0 += x1; x1 = rotl32(x1, 24); x1 ^= x0;
    x0 += k1; x1 += ks2 + 4u;
    x0 += x1; x1 = rotl32(x1, 13); x1 ^= x0;
    x0 += x1; x1 = rotl32(x1, 15); x1 ^= x0;
    x0 += x1; x1 = rotl32(x1, 26); x1 ^= x0;
    x0 += x1; x1 = rotl32(x1, 6);  x1 ^= x0;
    x0 += ks2; x1 += k0 + 5u;
    o0 = x0; o1 = x1;
}

struct RngKeys {
    uint32_t c0[NB], c1[NB];   // partitionable k2 keys: centers
    uint32_t n0[NB], n1[NB];   // partitionable k2 keys: neighbor draws
};

// partitionable random_bits(key, 32, ...): element u -> o0^o1, counter (0,u)
__device__ static inline uint32_t pbits32(uint32_t k0, uint32_t k1, uint32_t u) {
    uint32_t o0, o1;
    tf2x32(k0, k1, 0u, u, o0, o1);
    return o0 ^ o1;
}

// dense cell index: x in low bits. Coords for N(0,1) data stay in [11,52] ⊂ [0,63].
__device__ static inline int cellidx(const float* __restrict__ p) {
    int vx = ((int)floorf(p[0] * 4.0f) + 32) & 63;
    int vy = ((int)floorf(p[1] * 4.0f) + 32) & 63;
    int vz = ((int)floorf(p[2] * 4.0f) + 32) & 63;
    return vx | (vy << 6) | (vz << 12);
}

// cellv layout: int pairs [2*gc] = count, [2*gc+1] = start

// ---------------- P0: init cells + flag outputs -----------------
__global__ void k_zero(int2* __restrict__ cell, int* __restrict__ bctr,
                       float4* __restrict__ flags4) {
    int t = blockIdx.x * blockDim.x + threadIdx.x;   // exact: NB*CELLS
    cell[t] = make_int2(0, 0);
    if (t < (2 * NB * NPTS) / 4) flags4[t] = make_float4(0.f, 0.f, 0.f, 0.f);
    if (t < NB) bctr[t] = 0;
}

// ---------------- P1: count points per cell (+ cache cell index) -----------
__global__ void k_count(const float* __restrict__ pos, int* __restrict__ cellv,
                        int* __restrict__ cidxOf) {
    int t = blockIdx.x * blockDim.x + threadIdx.x;   // exact: NB*NPTS
    int b = t / NPTS;
    int cidx = cellidx(pos + (size_t)t * 3);
    cidxOf[t] = cidx;
    atomicAdd(&cellv[(((size_t)b << CLG) + cidx) * 2], 1);
}

// ---------------- P2: assign bucket starts (block scan, 1 atomic/block) ----
__global__ void k_starts(int* __restrict__ cellv, int* __restrict__ bctr) {
    __shared__ int sdata[256];
    __shared__ int sbase;
    int t = blockIdx.x * blockDim.x + threadIdx.x;   // exact: NB*CELLS
    int tid = threadIdx.x;
    int b = t >> CLG;                                // uniform per block
    int c = cellv[2 * (size_t)t];
    sdata[tid] = c;
    __syncthreads();
    for (int off = 1; off < 256; off <<= 1) {        // Hillis-Steele inclusive
        int x = (tid >= off) ? sdata[tid - off] : 0;
        __syncthreads();
        sdata[tid] += x;
        __syncthreads();
    }
    if (tid == 255) sbase = atomicAdd(&bctr[b], sdata[255]);
    __syncthreads();
    if (c > 0) {
        cellv[2 * (size_t)t + 1] = sbase + sdata[tid] - c;  // exclusive prefix
        cellv[2 * (size_t)t] = 0;                           // becomes fill counter
    }
}

// ---------------- P3: scatter arrival order -----------------
__global__ void k_scatter(const int* __restrict__ cidxOf, int* __restrict__ cellv,
                          int* __restrict__ listA) {
    int t = blockIdx.x * blockDim.x + threadIdx.x;   // exact: NB*NPTS
    int b = t / NPTS, i = t - b * NPTS;
    size_t gc = ((size_t)b << CLG) + cidxOf[t];
    int a = atomicAdd(&cellv[2 * gc], 1);            // restores count as side effect
    listA[(size_t)b * NPTS + cellv[2 * gc + 1] + a] = i;
}

// ---------------- P4: rank within cell -> index-sorted lists ------------
__global__ void k_rank(const int* __restrict__ cidxOf, const int* __restrict__ cellv,
                       const int* __restrict__ listA, int* __restrict__ listB) {
    int t = blockIdx.x * blockDim.x + threadIdx.x;   // exact: NB*NPTS
    int b = t / NPTS, i = t - b * NPTS;
    size_t gc = ((size_t)b << CLG) + cidxOf[t];
    int2 cs = ((const int2*)cellv)[gc];              // x=count, y=start
    const int* L = listA + (size_t)b * NPTS + cs.y;
    int rank = 0;
    for (int k = 0; k < cs.x; k++) rank += (L[k] < i) ? 1 : 0;
    listB[(size_t)b * NPTS + cs.y + rank] = i;
}

// ------- P5: centers + 27-bin lookup + cumsum + selection (fully fused) ----
// 32 threads per sample: lanes 0..26 read bins into LDS, all 32 select.
__global__ void k_sel(RngKeys keys, const int* __restrict__ cidxOf,
                      const int* __restrict__ cellv, const int* __restrict__ listB,
                      int* __restrict__ centers_ws, int* __restrict__ src_ws,
                      float* __restrict__ out_ctr, float* __restrict__ out_cf,
                      float* __restrict__ out_src, float* __restrict__ out_sf) {
    __shared__ int scnt[8][27];
    __shared__ int slo[8][27];
    int tid = threadIdx.x;                           // 256 threads = 8 samples
    int g = tid >> 5, n = tid & 31;
    int bs = blockIdx.x * 8 + g;                     // exact: NB*NS/8 blocks
    int b = bs >> 12, s = bs & (NS - 1);
    uint32_t lower_c = pbits32(keys.c0[b], keys.c1[b], (uint32_t)s);
    int c = (int)(lower_c % 100000u);                // randint multiplier==0 path
    int ccell = cidxOf[(size_t)b * NPTS + c];        // same 4B for 32 lanes -> L1
    if (n < 27) {
        // neighbor cell by integer offset (bin order: x slowest, matches ref)
        int ncell = (ccell + (n / 9 - 1) + ((n / 3) % 3 - 1) * 64
                           + (n % 3 - 1) * 4096) & CMASK;
        int2 cs = ((const int2*)cellv)[((size_t)b << CLG) + ncell];
        scnt[g][n] = cs.x;
        slo[g][n] = cs.y;
    }
    if (n == 0) {
        centers_ws[bs] = c;
        out_ctr[bs] = (float)c;
        out_cf[(size_t)b * NPTS + c] = 1.0f;
    }
    __syncthreads();
    uint32_t lower = pbits32(keys.n0[b], keys.n1[b], (uint32_t)(s * NN + n));
    int total = 0;
    #pragma unroll
    for (int i = 0; i < 27; i++) total += scnt[g][i];
    int r = (int)(lower & 0x3FFFFFFFu) % total;      // span=2^30 -> multiplier==0 path
    int slot = 0, prev = 0, acc = 0;
    #pragma unroll
    for (int i = 0; i < 27; i++) {
        acc += scnt[g][i];
        if (r >= acc) { slot = i + 1; prev = acc; }
    }
    int pos_in = slo[g][slot] + (r - prev);
    int src = listB[(size_t)b * NPTS + pos_in];
    int oi = bs * NN + n;
    src_ws[oi] = src;
    out_src[oi] = (float)src;
    out_sf[(size_t)b * NPTS + src] = 1.0f;
}

// ---- P6: output gather: 64 rows/block, 2 independent feat loads/thread ----
__global__ void k_gather(const float* __restrict__ pos, const float* __restrict__ feat,
                         const int* __restrict__ centers_ws, const int* __restrict__ src_ws,
                         float* __restrict__ out) {
    __shared__ float sbuf[64 * 67];                   // 17152 B
    int t = threadIdx.x;                              // 512 threads
    long long row0 = (long long)blockIdx.x * 64;      // exact: NB*NS*NN rows
    // two feat-quarter slots per thread -> 2 loads in flight (MLP)
    int g0 = t >> 4,          q0 = t & 15;
    int g1 = (t + 512) >> 4,  q1 = t & 15;            // (t+512)&15 == t&15
    long long rowA = row0 + g0, rowB = row0 + g1;
    int bA = (int)(rowA >> 17), bB = (int)(rowB >> 17);
    int srcA = src_ws[rowA];
    int srcB = src_ws[rowB];
    const float4 fvA = *(const float4*)(feat + ((size_t)bA * NPTS + srcA) * NCH + 4 * q0);
    const float4 fvB = *(const float4*)(feat + ((size_t)bB * NPTS + srcB) * NCH + 4 * q1);
    float* sbA = sbuf + g0 * 67;
    sbA[3 + 4 * q0 + 0] = fvA.x;
    sbA[3 + 4 * q0 + 1] = fvA.y;
    sbA[3 + 4 * q0 + 2] = fvA.z;
    sbA[3 + 4 * q0 + 3] = fvA.w;
    float* sbB = sbuf + g1 * 67;
    sbB[3 + 4 * q1 + 0] = fvB.x;
    sbB[3 + 4 * q1 + 1] = fvB.y;
    sbB[3 + 4 * q1 + 2] = fvB.z;
    sbB[3 + 4 * q1 + 3] = fvB.w;
    if (t < 192) {                                    // rel: 3 floats x 64 rows
        int g = t / 3, q = t - g * 3;
        long long row = row0 + g;
        int b = (int)(row >> 17);
        int u = (int)(row & (NS * NN - 1));
        int s = u >> 5;
        int src = src_ws[row];
        int ctr = centers_ws[b * NS + s];
        sbuf[g * 67 + q] = pos[((size_t)b * NPTS + src) * 3 + q]
                         - pos[((size_t)b * NPTS + ctr) * 3 + q];
    }
    __syncthreads();
    // 64*67 = 4288 floats = 1072 float4, contiguous & 16B-aligned per block.
    // Output is write-once, never re-read on device -> nontemporal (keep L3 for feat).
    f32x4* ob = (f32x4*)(out + (size_t)row0 * 67);
    const f32x4* sv = (const f32x4*)sbuf;
    __builtin_nontemporal_store(sv[t], &ob[t]);
    __builtin_nontemporal_store(sv[t + 512], &ob[t + 512]);
    if (t < 48) __builtin_nontemporal_store(sv[t + 1024], &ob[t + 1024]);
}

extern "C" void kernel_launch(void* const* d_in, const int* in_sizes, int n_in,
                              void* d_out, int out_size, void* d_ws, size_t ws_size,
                              hipStream_t stream) {
    (void)in_sizes; (void)n_in; (void)out_size; (void)ws_size;
    const float* pos = (const float*)d_in[0];
    const float* feat = (const float*)d_in[1];
    float* out = (float*)d_out;

    // ---- host-side JAX key-chain (threefry partitionable mode) ----
    RngKeys keys;
    for (int b = 0; b < NB; b++) {
        uint32_t rk0, rk1, kc0, kc1, kn0, kn1;
        tf2x32(0u, 42u, 0u, (uint32_t)b, rk0, rk1);
        tf2x32(rk0, rk1, 0u, 0u, kc0, kc1);
        tf2x32(rk0, rk1, 0u, 1u, kn0, kn1);
        tf2x32(kc0, kc1, 0u, 1u, keys.c0[b], keys.c1[b]);
        tf2x32(kn0, kn1, 0u, 1u, keys.n0[b], keys.n1[b]);
    }

    // ---- workspace layout (~30.4 MB) ----
    int* cellv      = (int*)d_ws;                      // NB*CELLS int2 (16 MB)
    int* bctr       = cellv + (size_t)NB * CELLS * 2;  // NB
    int* cidxOf     = bctr + NB;                       // NB*NPTS
    int* listA      = cidxOf + (size_t)NB * NPTS;      // NB*NPTS
    int* listB      = listA + (size_t)NB * NPTS;       // NB*NPTS
    int* centers_ws = listB + (size_t)NB * NPTS;       // NB*NS
    int* src_ws     = centers_ws + (size_t)NB * NS;    // NB*NS*NN

    k_zero   <<<(NB * CELLS) / 256, 256, 0, stream>>>((int2*)cellv, bctr,
                                                      (float4*)(out + OUT_CF));
    k_count  <<<(NB * NPTS) / 256, 256, 0, stream>>>(pos, cellv, cidxOf);
    k_starts <<<(NB * CELLS) / 256, 256, 0, stream>>>(cellv, bctr);
    k_scatter<<<(NB * NPTS) / 256, 256, 0, stream>>>(cidxOf, cellv, listA);
    k_rank   <<<(NB * NPTS) / 256, 256, 0, stream>>>(cidxOf, cellv, listA, listB);
    k_sel    <<<(NB * NS) / 8, 256, 0, stream>>>(keys, cidxOf, cellv, listB,
                                                 centers_ws, src_ws,
                                                 out + OUT_CTR, out + OUT_CF,
                                                 out + OUT_SRC, out + OUT_SF);
    k_gather <<<(NB * NS * NN) / 64, 512, 0, stream>>>(pos, feat, centers_ws, src_ws, out);
}

// Round 10
// 372.875 us; speedup vs baseline: 1.4430x; 1.4430x over previous
//
#include <hip/hip_runtime.h>
#include <stdint.h>

#define NB 8
#define NPTS 100000
#define NS 4096
#define NN 32
#define NCH 64
#define CLG 18
#define CELLS (1 << CLG)           // 64^3 dense voxel cells per batch
#define CMASK (CELLS - 1)

// d_out float layout (element offsets)
#define OUT_MAIN 0ull                          // [8,4096,32,67]
#define OUT_SRC  70254592ull                   // [8,4096,32]
#define OUT_CTR  71303168ull                   // [8,4096]
#define OUT_CF   71335936ull                   // [8,100000]
#define OUT_SF   72135936ull                   // [8,100000]

typedef float f32x4 __attribute__((ext_vector_type(4)));

__host__ __device__ static inline uint32_t rotl32(uint32_t v, int d) {
    return (v << d) | (v >> (32 - d));
}

// JAX threefry2x32 (5 groups of 4 rounds), exact.
__host__ __device__ static inline void tf2x32(uint32_t k0, uint32_t k1,
                                              uint32_t x0, uint32_t x1,
                                              uint32_t& o0, uint32_t& o1) {
    uint32_t ks2 = k0 ^ k1 ^ 0x1BD11BDAu;
    x0 += k0; x1 += k1;
    x0 += x1; x1 = rotl32(x1, 13); x1 ^= x0;
    x0 += x1; x1 = rotl32(x1, 15); x1 ^= x0;
    x0 += x1; x1 = rotl32(x1, 26); x1 ^= x0;
    x0 += x1; x1 = rotl32(x1, 6);  x1 ^= x0;
    x0 += k1; x1 += ks2 + 1u;
    x0 += x1; x1 = rotl32(x1, 17); x1 ^= x0;
    x0 += x1; x1 = rotl32(x1, 29); x1 ^= x0;
    x0 += x1; x1 = rotl32(x1, 16); x1 ^= x0;
    x0 += x1; x1 = rotl32(x1, 24); x1 ^= x0;
    x0 += ks2; x1 += k0 + 2u;
    x0 += x1; x1 = rotl32(x1, 13); x1 ^= x0;
    x0 += x1; x1 = rotl32(x1, 15); x1 ^= x0;
    x0 += x1; x1 = rotl32(x1, 26); x1 ^= x0;
    x0 += x1; x1 = rotl32(x1, 6);  x1 ^= x0;
    x0 += k0; x1 += k1 + 3u;
    x0 += x1; x1 = rotl32(x1, 17); x1 ^= x0;
    x0 += x1; x1 = rotl32(x1, 29); x1 ^= x0;
    x0 += x1; x1 = rotl32(x1, 16); x1 ^= x0;
    x0 += x1; x1 = rotl32(x1, 24); x1 ^= x0;
    x0 += k1; x1 += ks2 + 4u;
    x0 += x1; x1 = rotl32(x1, 13); x1 ^= x0;
    x0 += x1; x1 = rotl32(x1, 15); x1 ^= x0;
    x0 += x1; x1 = rotl32(x1, 26); x1 ^= x0;
    x0 += x1; x1 = rotl32(x1, 6);  x1 ^= x0;
    x0 += ks2; x1 += k0 + 5u;
    o0 = x0; o1 = x1;
}

struct RngKeys {
    uint32_t c0[NB], c1[NB];   // partitionable k2 keys: centers
    uint32_t n0[NB], n1[NB];   // partitionable k2 keys: neighbor draws
};

// partitionable random_bits(key, 32, ...): element u -> o0^o1, counter (0,u)
__device__ static inline uint32_t pbits32(uint32_t k0, uint32_t k1, uint32_t u) {
    uint32_t o0, o1;
    tf2x32(k0, k1, 0u, u, o0, o1);
    return o0 ^ o1;
}

// dense cell index: x in low bits. Coords for N(0,1) data stay in [11,52] ⊂ [0,63].
__device__ static inline int cellidx(const float* __restrict__ p) {
    int vx = ((int)floorf(p[0] * 4.0f) + 32) & 63;
    int vy = ((int)floorf(p[1] * 4.0f) + 32) & 63;
    int vz = ((int)floorf(p[2] * 4.0f) + 32) & 63;
    return vx | (vy << 6) | (vz << 12);
}

// ---------------- P0: init counts + flag outputs -----------------
__global__ void k_zero(int* __restrict__ cnt, int* __restrict__ bctr,
                       float4* __restrict__ flags4) {
    int t = blockIdx.x * blockDim.x + threadIdx.x;   // exact: NB*CELLS
    cnt[t] = 0;
    if (t < (2 * NB * NPTS) / 4) flags4[t] = make_float4(0.f, 0.f, 0.f, 0.f);
    if (t < NB) bctr[t] = 0;
}

// ---------------- P1: count points per cell (+ cache cell index) -----------
__global__ void k_count(const float* __restrict__ pos, int* __restrict__ cnt,
                        int* __restrict__ cidxOf) {
    int t = blockIdx.x * blockDim.x + threadIdx.x;   // exact: NB*NPTS
    int b = t / NPTS;
    int cidx = cellidx(pos + (size_t)t * 3);
    cidxOf[t] = cidx;
    atomicAdd(&cnt[((size_t)b << CLG) + cidx], 1);
}

// ------ P2: write cursors = cell start (block scan, 1 atomic/block) --------
// cnt[] stays intact (rank/sel need it); cursor[] becomes the fill cursor.
__global__ void k_starts(const int* __restrict__ cnt, int* __restrict__ cursor,
                         int* __restrict__ bctr) {
    __shared__ int sdata[256];
    __shared__ int sbase;
    int t = blockIdx.x * blockDim.x + threadIdx.x;   // exact: NB*CELLS
    int tid = threadIdx.x;
    int b = t >> CLG;                                // uniform per block
    int c = cnt[t];
    sdata[tid] = c;
    __syncthreads();
    for (int off = 1; off < 256; off <<= 1) {        // Hillis-Steele inclusive
        int x = (tid >= off) ? sdata[tid - off] : 0;
        __syncthreads();
        sdata[tid] += x;
        __syncthreads();
    }
    if (tid == 255) sbase = atomicAdd(&bctr[b], sdata[255]);
    __syncthreads();
    cursor[t] = sbase + sdata[tid] - c;              // exclusive prefix (start)
}

// ------ P3: scatter arrival order (single atomic, no contended reads) ------
__global__ void k_scatter(const int* __restrict__ cidxOf, int* __restrict__ cursor,
                          int* __restrict__ listA) {
    int t = blockIdx.x * blockDim.x + threadIdx.x;   // exact: NB*NPTS
    int b = t / NPTS, i = t - b * NPTS;
    size_t gc = ((size_t)b << CLG) + cidxOf[t];
    int a = atomicAdd(&cursor[gc], 1);               // returns absolute position
    listA[(size_t)b * NPTS + a] = i;
}

// ---------------- P4: rank within cell -> index-sorted lists ------------
// After scatter, cursor[gc] == start + cnt[gc] (end).
__global__ void k_rank(const int* __restrict__ cidxOf, const int* __restrict__ cnt,
                       const int* __restrict__ cursor,
                       const int* __restrict__ listA, int* __restrict__ listB) {
    int t = blockIdx.x * blockDim.x + threadIdx.x;   // exact: NB*NPTS
    int b = t / NPTS, i = t - b * NPTS;
    size_t gc = ((size_t)b << CLG) + cidxOf[t];
    int c = cnt[gc];
    int s0 = cursor[gc] - c;                         // start
    const int* L = listA + (size_t)b * NPTS + s0;
    int rank = 0;
    for (int k = 0; k < c; k++) rank += (L[k] < i) ? 1 : 0;
    listB[(size_t)b * NPTS + s0 + rank] = i;
}

// ------- P5: centers + 27-bin lookup + cumsum + selection (fully fused) ----
// 32 threads per sample: lanes 0..26 read bins into LDS, all 32 select.
__global__ void k_sel(RngKeys keys, const int* __restrict__ cidxOf,
                      const int* __restrict__ cnt, const int* __restrict__ cursor,
                      const int* __restrict__ listB,
                      int* __restrict__ centers_ws, int* __restrict__ src_ws,
                      float* __restrict__ out_ctr, float* __restrict__ out_cf,
                      float* __restrict__ out_src, float* __restrict__ out_sf) {
    __shared__ int scnt[8][27];
    __shared__ int slo[8][27];
    int tid = threadIdx.x;                           // 256 threads = 8 samples
    int g = tid >> 5, n = tid & 31;
    int bs = blockIdx.x * 8 + g;                     // exact: NB*NS/8 blocks
    int b = bs >> 12, s = bs & (NS - 1);
    uint32_t lower_c = pbits32(keys.c0[b], keys.c1[b], (uint32_t)s);
    int c = (int)(lower_c % 100000u);                // randint multiplier==0 path
    int ccell = cidxOf[(size_t)b * NPTS + c];        // same 4B for 32 lanes -> L1
    if (n < 27) {
        // neighbor cell by integer offset (bin order: x slowest, matches ref)
        int ncell = (ccell + (n / 9 - 1) + ((n / 3) % 3 - 1) * 64
                           + (n % 3 - 1) * 4096) & CMASK;
        size_t gc = ((size_t)b << CLG) + ncell;
        int cc = cnt[gc];
        scnt[g][n] = cc;
        slo[g][n] = cursor[gc] - cc;                 // start
    }
    if (n == 0) {
        centers_ws[bs] = c;
        out_ctr[bs] = (float)c;
        out_cf[(size_t)b * NPTS + c] = 1.0f;
    }
    __syncthreads();
    uint32_t lower = pbits32(keys.n0[b], keys.n1[b], (uint32_t)(s * NN + n));
    int total = 0;
    #pragma unroll
    for (int i = 0; i < 27; i++) total += scnt[g][i];
    int r = (int)(lower & 0x3FFFFFFFu) % total;      // span=2^30 -> multiplier==0 path
    int slot = 0, prev = 0, acc = 0;
    #pragma unroll
    for (int i = 0; i < 27; i++) {
        acc += scnt[g][i];
        if (r >= acc) { slot = i + 1; prev = acc; }
    }
    int pos_in = slo[g][slot] + (r - prev);
    int src = listB[(size_t)b * NPTS + pos_in];
    int oi = bs * NN + n;
    src_ws[oi] = src;
    out_src[oi] = (float)src;
    out_sf[(size_t)b * NPTS + src] = 1.0f;
}

// ---- P6: output gather: 64 rows/block, 2 independent feat loads/thread ----
__global__ void k_gather(const float* __restrict__ pos, const float* __restrict__ feat,
                         const int* __restrict__ centers_ws, const int* __restrict__ src_ws,
                         float* __restrict__ out) {
    __shared__ float sbuf[64 * 67];                   // 17152 B
    int t = threadIdx.x;                              // 512 threads
    long long row0 = (long long)blockIdx.x * 64;      // exact: NB*NS*NN rows
    // two feat-quarter slots per thread -> 2 loads in flight (MLP)
    int g0 = t >> 4,          q0 = t & 15;
    int g1 = (t + 512) >> 4,  q1 = t & 15;            // (t+512)&15 == t&15
    long long rowA = row0 + g0, rowB = row0 + g1;
    int bA = (int)(rowA >> 17), bB = (int)(rowB >> 17);
    int srcA = src_ws[rowA];
    int srcB = src_ws[rowB];
    const float4 fvA = *(const float4*)(feat + ((size_t)bA * NPTS + srcA) * NCH + 4 * q0);
    const float4 fvB = *(const float4*)(feat + ((size_t)bB * NPTS + srcB) * NCH + 4 * q1);
    float* sbA = sbuf + g0 * 67;
    sbA[3 + 4 * q0 + 0] = fvA.x;
    sbA[3 + 4 * q0 + 1] = fvA.y;
    sbA[3 + 4 * q0 + 2] = fvA.z;
    sbA[3 + 4 * q0 + 3] = fvA.w;
    float* sbB = sbuf + g1 * 67;
    sbB[3 + 4 * q1 + 0] = fvB.x;
    sbB[3 + 4 * q1 + 1] = fvB.y;
    sbB[3 + 4 * q1 + 2] = fvB.z;
    sbB[3 + 4 * q1 + 3] = fvB.w;
    if (t < 192) {                                    // rel: 3 floats x 64 rows
        int g = t / 3, q = t - g * 3;
        long long row = row0 + g;
        int b = (int)(row >> 17);
        int u = (int)(row & (NS * NN - 1));
        int s = u >> 5;
        int src = src_ws[row];
        int ctr = centers_ws[b * NS + s];
        sbuf[g * 67 + q] = pos[((size_t)b * NPTS + src) * 3 + q]
                         - pos[((size_t)b * NPTS + ctr) * 3 + q];
    }
    __syncthreads();
    // 64*67 = 4288 floats = 1072 float4, contiguous & 16B-aligned per block.
    // Output is write-once, never re-read on device -> nontemporal (keep L3 for feat).
    f32x4* ob = (f32x4*)(out + (size_t)row0 * 67);
    const f32x4* sv = (const f32x4*)sbuf;
    __builtin_nontemporal_store(sv[t], &ob[t]);
    __builtin_nontemporal_store(sv[t + 512], &ob[t + 512]);
    if (t < 48) __builtin_nontemporal_store(sv[t + 1024], &ob[t + 1024]);
}

extern "C" void kernel_launch(void* const* d_in, const int* in_sizes, int n_in,
                              void* d_out, int out_size, void* d_ws, size_t ws_size,
                              hipStream_t stream) {
    (void)in_sizes; (void)n_in; (void)out_size; (void)ws_size;
    const float* pos = (const float*)d_in[0];
    const float* feat = (const float*)d_in[1];
    float* out = (float*)d_out;

    // ---- host-side JAX key-chain (threefry partitionable mode) ----
    RngKeys keys;
    for (int b = 0; b < NB; b++) {
        uint32_t rk0, rk1, kc0, kc1, kn0, kn1;
        tf2x32(0u, 42u, 0u, (uint32_t)b, rk0, rk1);
        tf2x32(rk0, rk1, 0u, 0u, kc0, kc1);
        tf2x32(rk0, rk1, 0u, 1u, kn0, kn1);
        tf2x32(kc0, kc1, 0u, 1u, keys.c0[b], keys.c1[b]);
        tf2x32(kn0, kn1, 0u, 1u, keys.n0[b], keys.n1[b]);
    }

    // ---- workspace layout (~30.4 MB) ----
    int* cnt        = (int*)d_ws;                      // NB*CELLS (8 MB)
    int* cursor     = cnt + (size_t)NB * CELLS;        // NB*CELLS (8 MB)
    int* bctr       = cursor + (size_t)NB * CELLS;     // NB
    int* cidxOf     = bctr + NB;                       // NB*NPTS
    int* listA      = cidxOf + (size_t)NB * NPTS;      // NB*NPTS
    int* listB      = listA + (size_t)NB * NPTS;       // NB*NPTS
    int* centers_ws = listB + (size_t)NB * NPTS;       // NB*NS
    int* src_ws     = centers_ws + (size_t)NB * NS;    // NB*NS*NN

    k_zero   <<<(NB * CELLS) / 256, 256, 0, stream>>>(cnt, bctr,
                                                      (float4*)(out + OUT_CF));
    k_count  <<<(NB * NPTS) / 256, 256, 0, stream>>>(pos, cnt, cidxOf);
    k_starts <<<(NB * CELLS) / 256, 256, 0, stream>>>(cnt, cursor, bctr);
    k_scatter<<<(NB * NPTS) / 256, 256, 0, stream>>>(cidxOf, cursor, listA);
    k_rank   <<<(NB * NPTS) / 256, 256, 0, stream>>>(cidxOf, cnt, cursor, listA, listB);
    k_sel    <<<(NB * NS) / 8, 256, 0, stream>>>(keys, cidxOf, cnt, cursor, listB,
                                                 centers_ws, src_ws,
                                                 out + OUT_CTR, out + OUT_CF,
                                                 out + OUT_SRC, out + OUT_SF);
    k_gather <<<(NB * NS * NN) / 64, 512, 0, stream>>>(pos, feat, centers_ws, src_ws, out);
}